// Round 1
// baseline (226.028 us; speedup 1.0000x reference)
//
#include <hip/hip_runtime.h>

#define DEV __device__ __forceinline__

typedef _Float16 f16x8 __attribute__((ext_vector_type(8)));
typedef _Float16 f16x4 __attribute__((ext_vector_type(4)));
typedef unsigned short u16x8 __attribute__((ext_vector_type(8)));
typedef float f32x4 __attribute__((ext_vector_type(4)));

// async global->LDS, 16B per lane. LDS dest must be wave-uniform base (+lane*16 in HW).
DEV void glds16(const void* g, void* l) {
    __builtin_amdgcn_global_load_lds(
        (const __attribute__((address_space(1))) void*)g,
        (__attribute__((address_space(3))) void*)l, 16, 0, 0);
}

// ---------------------------------------------------------------------------
// cast fp32 -> fp16, 4 elems/thread
__global__ __launch_bounds__(256) void cast_f32_f16(const float* __restrict__ src,
                                                    _Float16* __restrict__ dst, int n4) {
    const int i = blockIdx.x * 256 + threadIdx.x;
    if (i >= n4) return;
    const float4 v = ((const float4*)src)[i];
    f16x4 o = { (_Float16)v.x, (_Float16)v.y, (_Float16)v.z, (_Float16)v.w };
    *(f16x4*)(dst + (size_t)i * 4) = o;
}

// ---------------------------------------------------------------------------
// Fold LoRA (I + A B) into Q/V sections of Wqkv; fold softmax scale into Q.
// W'[h*64+i, c] = scale * ( W[h*64+i,c] + sum_r B[r,i] * sum_j A[j,r] W[h*64+j,c] )
__global__ __launch_bounds__(256) void prep_w(const float* __restrict__ W,
                                              const float* __restrict__ Aq,
                                              const float* __restrict__ Bq,
                                              const float* __restrict__ Av,
                                              const float* __restrict__ Bv,
                                              _Float16* __restrict__ Wb) {
    const int bx = blockIdx.x;         // 0..23: 12 Q heads then 12 V heads
    const int sec = bx / 12;           // 0 = Q, 1 = V
    const int h = bx - sec * 12;
    const float* Am = sec ? Av : Aq;   // [64][4]
    const float* Bm = sec ? Bv : Bq;   // [4][64]
    const int base = sec ? (1536 + h * 64) : (h * 64);
    const float scale = sec ? 1.0f : 0.125f;   // hd^-0.5 = 64^-0.5 folded into Q
    for (int c = threadIdx.x; c < 768; c += 256) {
        float t0 = 0.f, t1 = 0.f, t2 = 0.f, t3 = 0.f;
        for (int j = 0; j < 64; ++j) {
            const float w = W[(size_t)(base + j) * 768 + c];
            t0 += Am[j * 4 + 0] * w;
            t1 += Am[j * 4 + 1] * w;
            t2 += Am[j * 4 + 2] * w;
            t3 += Am[j * 4 + 3] * w;
        }
        for (int i = 0; i < 64; ++i) {
            const float w = W[(size_t)(base + i) * 768 + c];
            const float val = w + t0 * Bm[i] + t1 * Bm[64 + i] + t2 * Bm[128 + i] + t3 * Bm[192 + i];
            Wb[(size_t)(base + i) * 768 + c] = (_Float16)(val * scale);
        }
    }
}

// ---------------------------------------------------------------------------
// 128x128 NT GEMM, BK=64, 4 waves (2x2 of 64x64), fp16 in / fp32 acc.
// EPI 0: scatter into QKV [3][96][1024][64] fp16.  EPI 1: +bias, fp32 out [M][768].
template <int EPI>
__global__ __launch_bounds__(256) void gemm_nt(const _Float16* __restrict__ A,
                                               const _Float16* __restrict__ B,
                                               int Kdim, void* __restrict__ Cout,
                                               const float* __restrict__ bias) {
    __shared__ __align__(16) _Float16 As[128 * 64];
    __shared__ __align__(16) _Float16 Bs[128 * 64];
    const int tid = threadIdx.x;
    const int lane = tid & 63, wid = tid >> 6;
    const int l15 = lane & 15, l16 = lane >> 4;
    const int m0 = blockIdx.x << 7, n0 = blockIdx.y << 7;
    const int wm = (wid >> 1) << 6, wn = (wid & 1) << 6;

    f32x4 acc[4][4];
#pragma unroll
    for (int i = 0; i < 4; ++i)
#pragma unroll
        for (int j = 0; j < 4; ++j) acc[i][j] = (f32x4){0.f, 0.f, 0.f, 0.f};

    for (int k0 = 0; k0 < Kdim; k0 += 64) {
        __syncthreads();
        // stage A,B tiles: linear LDS dest, inverse-swizzled global source (rule 21)
#pragma unroll
        for (int rr = 0; rr < 4; ++rr) {
            const int slot = (rr << 8) + tid;          // 0..1023
            const int row = slot >> 3, sl = slot & 7;  // 8B-elem slices of 8
            const int ldsb = ((rr << 8) + (wid << 6)) << 4;  // wave-uniform byte base
            glds16(A + (size_t)(m0 + row) * Kdim + k0 + ((sl ^ (row & 7)) << 3),
                   (char*)As + ldsb);
            glds16(B + (size_t)(n0 + row) * Kdim + k0 + ((sl ^ (row & 7)) << 3),
                   (char*)Bs + ldsb);
        }
        __syncthreads();
#pragma unroll
        for (int kh = 0; kh < 2; ++kh) {
            f16x8 af[4], bfr[4];
#pragma unroll
            for (int i = 0; i < 4; ++i) {
                const int ra = wm + i * 16 + l15;
                af[i] = *(const f16x8*)((const char*)As + ra * 128 +
                                        ((((kh << 2) + l16) ^ (ra & 7)) << 4));
                const int rb = wn + i * 16 + l15;
                bfr[i] = *(const f16x8*)((const char*)Bs + rb * 128 +
                                         ((((kh << 2) + l16) ^ (rb & 7)) << 4));
            }
#pragma unroll
            for (int i = 0; i < 4; ++i)
#pragma unroll
                for (int j = 0; j < 4; ++j)
                    acc[i][j] = __builtin_amdgcn_mfma_f32_16x16x32_f16(af[i], bfr[j], acc[i][j], 0, 0, 0);
        }
    }

    if (EPI == 0) {
        _Float16* qkv = (_Float16*)Cout;
#pragma unroll
        for (int j = 0; j < 4; ++j) {
            const int col = n0 + wn + j * 16 + l15;   // 0..2303 = [3][12][64]
            const int which = col / 768;
            const int rem = col - which * 768;
            const int hh = rem >> 6, d = rem & 63;
#pragma unroll
            for (int i = 0; i < 4; ++i)
#pragma unroll
                for (int r = 0; r < 4; ++r) {
                    const int row = m0 + wm + i * 16 + (l16 << 2) + r;  // b*1024+n
                    const int b = row >> 10, n = row & 1023;
                    const size_t idx =
                        (((size_t)which * 96 + (size_t)b * 12 + hh) * 1024 + n) * 64 + d;
                    qkv[idx] = (_Float16)acc[i][j][r];
                }
        }
    } else {
        float* out = (float*)Cout;
#pragma unroll
        for (int j = 0; j < 4; ++j) {
            const int col = n0 + wn + j * 16 + l15;
            const float bv = bias[col];
#pragma unroll
            for (int i = 0; i < 4; ++i)
#pragma unroll
                for (int r = 0; r < 4; ++r) {
                    const int row = m0 + wm + i * 16 + (l16 << 2) + r;
                    out[(size_t)row * 768 + col] = acc[i][j][r] + bv;
                }
        }
    }
}

// ---------------------------------------------------------------------------
// Flash attention: 4 waves x 32 q-rows = 128-row Q tile, KV tiles of 128, d=64.
// Scale already folded into Q. Q frags live in registers; K via glds (swizzled);
// V reg-transposed into LDS; P round-trips through per-wave LDS (swizzled).
__global__ __launch_bounds__(256) void attn_kernel(const _Float16* __restrict__ Qg,
                                                   const _Float16* __restrict__ Kg,
                                                   const _Float16* __restrict__ Vg,
                                                   _Float16* __restrict__ AO) {
    __shared__ __align__(16) _Float16 Ks[128 * 64];
    __shared__ __align__(16) _Float16 Vt[64 * 128];
    __shared__ __align__(16) _Float16 Ps[4][32 * 128];

    const int tid = threadIdx.x, lane = tid & 63, wid = tid >> 6;
    const int l15 = lane & 15, l16 = lane >> 4;
    const int bh = blockIdx.y;             // b*12+h
    const int q0 = blockIdx.x << 7;
    const size_t qbase = ((size_t)bh * 1024 + q0) * 64;

    // hoist Q fragments (wave owns rows wid*32 .. +31)
    f16x8 qf[2][2];
#pragma unroll
    for (int mt = 0; mt < 2; ++mt)
#pragma unroll
        for (int kh = 0; kh < 2; ++kh) {
            const int row = (wid << 5) + mt * 16 + l15;
            qf[mt][kh] = *(const f16x8*)(Qg + qbase + (size_t)row * 64 + (((kh << 2) + l16) << 3));
        }

    f32x4 o[2][4];
    float m_run[2][4], l_run[2][4];
#pragma unroll
    for (int mt = 0; mt < 2; ++mt)
#pragma unroll
        for (int rg = 0; rg < 4; ++rg) {
            m_run[mt][rg] = -INFINITY;
            l_run[mt][rg] = 0.f;
        }
#pragma unroll
    for (int mt = 0; mt < 2; ++mt)
#pragma unroll
        for (int nf = 0; nf < 4; ++nf) o[mt][nf] = (f32x4){0.f, 0.f, 0.f, 0.f};

    char* Pb = (char*)&Ps[wid][0];

    for (int kt = 0; kt < 8; ++kt) {
        __syncthreads();
        const size_t kvbase = ((size_t)bh * 1024 + (size_t)kt * 128) * 64;
        // stage K (swizzled via pre-swizzled source)
#pragma unroll
        for (int rr = 0; rr < 4; ++rr) {
            const int slot = (rr << 8) + tid;
            const int row = slot >> 3, sl = slot & 7;
            glds16(Kg + kvbase + (size_t)row * 64 + ((sl ^ (row & 7)) << 3),
                   (char*)Ks + (((rr << 8) + (wid << 6)) << 4));
        }
        // stage V transposed: Vt[d][kv], pack kv pairs into b32 writes
#pragma unroll
        for (int it = 0; it < 2; ++it) {
            const int p = (it << 8) + tid;           // 0..511
            const int kv2 = p & 63, d8 = p >> 6;     // kv pair, d slice of 8
            const u16x8 v0 = *(const u16x8*)(Vg + kvbase + (size_t)(kv2 * 2) * 64 + (d8 << 3));
            const u16x8 v1 = *(const u16x8*)(Vg + kvbase + (size_t)(kv2 * 2 + 1) * 64 + (d8 << 3));
#pragma unroll
            for (int j = 0; j < 8; ++j) {
                const int d = (d8 << 3) + j;
                const unsigned pk = (unsigned)v0[j] | ((unsigned)v1[j] << 16);
                *(unsigned*)((char*)Vt + ((d * 256 + kv2 * 4) ^ ((d & 7) << 4))) = pk;
            }
        }
        __syncthreads();

        // S = Q K^T  (scale folded into Q)
        f32x4 s[2][8];
#pragma unroll
        for (int mt = 0; mt < 2; ++mt)
#pragma unroll
            for (int nf = 0; nf < 8; ++nf) s[mt][nf] = (f32x4){0.f, 0.f, 0.f, 0.f};
#pragma unroll
        for (int kh = 0; kh < 2; ++kh)
#pragma unroll
            for (int nf = 0; nf < 8; ++nf) {
                const int rb = nf * 16 + l15;
                const f16x8 bfr = *(const f16x8*)((const char*)Ks + rb * 128 +
                                                  ((((kh << 2) + l16) ^ (rb & 7)) << 4));
                s[0][nf] = __builtin_amdgcn_mfma_f32_16x16x32_f16(qf[0][kh], bfr, s[0][nf], 0, 0, 0);
                s[1][nf] = __builtin_amdgcn_mfma_f32_16x16x32_f16(qf[1][kh], bfr, s[1][nf], 0, 0, 0);
            }

        // online softmax (rows live on 16-lane groups; reduce over l15)
        float fac[2][4];
#pragma unroll
        for (int mt = 0; mt < 2; ++mt)
#pragma unroll
            for (int rg = 0; rg < 4; ++rg) {
                float mx = s[mt][0][rg];
#pragma unroll
                for (int nf = 1; nf < 8; ++nf) mx = fmaxf(mx, s[mt][nf][rg]);
                mx = fmaxf(mx, __shfl_xor(mx, 1));
                mx = fmaxf(mx, __shfl_xor(mx, 2));
                mx = fmaxf(mx, __shfl_xor(mx, 4));
                mx = fmaxf(mx, __shfl_xor(mx, 8));
                const float mnew = fmaxf(m_run[mt][rg], mx);
                const float f = __expf(m_run[mt][rg] - mnew);
                fac[mt][rg] = f;
                float sum = 0.f;
#pragma unroll
                for (int nf = 0; nf < 8; ++nf) {
                    const float p0 = __expf(s[mt][nf][rg] - mnew);
                    s[mt][nf][rg] = p0;
                    sum += p0;
                }
                sum += __shfl_xor(sum, 1);
                sum += __shfl_xor(sum, 2);
                sum += __shfl_xor(sum, 4);
                sum += __shfl_xor(sum, 8);
                l_run[mt][rg] = l_run[mt][rg] * f + sum;
                m_run[mt][rg] = mnew;
            }

        // write P (fp16) to per-wave LDS, swizzled
#pragma unroll
        for (int mt = 0; mt < 2; ++mt)
#pragma unroll
            for (int nf = 0; nf < 8; ++nf)
#pragma unroll
                for (int rg = 0; rg < 4; ++rg) {
                    const int row = mt * 16 + (l16 << 2) + rg;
                    const int col = nf * 16 + l15;
                    *(_Float16*)(Pb + ((row * 256 + col * 2) ^ ((row & 7) << 4))) =
                        (_Float16)s[mt][nf][rg];
                }

        // rescale O
#pragma unroll
        for (int mt = 0; mt < 2; ++mt)
#pragma unroll
            for (int nf = 0; nf < 4; ++nf)
#pragma unroll
                for (int rg = 0; rg < 4; ++rg) o[mt][nf][rg] *= fac[mt][rg];

        asm volatile("s_waitcnt lgkmcnt(0)" ::: "memory");

        // O += P @ V
#pragma unroll
        for (int ks = 0; ks < 4; ++ks) {
            f16x8 vf[4];
#pragma unroll
            for (int nf = 0; nf < 4; ++nf) {
                const int dc = nf * 16 + l15;
                vf[nf] = *(const f16x8*)((const char*)Vt + dc * 256 +
                                         ((((ks << 2) + l16) ^ (dc & 7)) << 4));
            }
#pragma unroll
            for (int mt = 0; mt < 2; ++mt) {
                const int prow = mt * 16 + l15;
                const f16x8 pa = *(const f16x8*)(Pb + prow * 256 +
                                                 ((((ks << 2) + l16) ^ (prow & 7)) << 4));
#pragma unroll
                for (int nf = 0; nf < 4; ++nf)
                    o[mt][nf] = __builtin_amdgcn_mfma_f32_16x16x32_f16(pa, vf[nf], o[mt][nf], 0, 0, 0);
            }
        }
    }

    // epilogue: AO[b, n, h*64+d] = O / l
    const int b = bh / 12, h = bh - (bh / 12) * 12;
#pragma unroll
    for (int mt = 0; mt < 2; ++mt)
#pragma unroll
        for (int rg = 0; rg < 4; ++rg) {
            const float inv = 1.0f / l_run[mt][rg];
            const int n = q0 + (wid << 5) + mt * 16 + (l16 << 2) + rg;
#pragma unroll
            for (int nf = 0; nf < 4; ++nf) {
                const int d = nf * 16 + l15;
                AO[((size_t)b * 1024 + n) * 768 + h * 64 + d] = (_Float16)(o[mt][nf][rg] * inv);
            }
        }
}

// ---------------------------------------------------------------------------
extern "C" void kernel_launch(void* const* d_in, const int* in_sizes, int n_in,
                              void* d_out, int out_size, void* d_ws, size_t ws_size,
                              hipStream_t stream) {
    (void)in_sizes; (void)n_in; (void)out_size; (void)ws_size;
    const float* x     = (const float*)d_in[0];
    const float* Wqkv  = (const float*)d_in[1];
    const float* Wproj = (const float*)d_in[2];
    const float* bproj = (const float*)d_in[3];
    const float* Aq    = (const float*)d_in[4];
    const float* Bq    = (const float*)d_in[5];
    const float* Av    = (const float*)d_in[6];
    const float* Bv    = (const float*)d_in[7];

    // workspace layout (fp16 elements)
    _Float16* Xb     = (_Float16*)d_ws;          // [8192][768]
    _Float16* Wqkvb  = Xb + 6291456;             // [2304][768]
    _Float16* Wprojb = Wqkvb + 1769472;          // [768][768]
    _Float16* QKV    = Wprojb + 589824;          // [3][96][1024][64]
    _Float16* AO     = QKV + 18874368;           // [8192][768]
    float* out = (float*)d_out;

    cast_f32_f16<<<6144, 256, 0, stream>>>(x, Xb, 1572864);
    cast_f32_f16<<<576, 256, 0, stream>>>(Wqkv + 589824, Wqkvb + 589824, 147456);  // K rows
    cast_f32_f16<<<576, 256, 0, stream>>>(Wproj, Wprojb, 147456);
    prep_w<<<24, 256, 0, stream>>>(Wqkv, Aq, Bq, Av, Bv, Wqkvb);

    gemm_nt<0><<<dim3(64, 18), 256, 0, stream>>>(Xb, Wqkvb, 768, (void*)QKV, nullptr);
    attn_kernel<<<dim3(8, 96), 256, 0, stream>>>(QKV, QKV + 6291456, QKV + 12582912, AO);
    gemm_nt<1><<<dim3(64, 6), 256, 0, stream>>>(AO, Wprojb, 768, (void*)out, bproj);
}

// Round 2
// 214.983 us; speedup vs baseline: 1.0514x; 1.0514x over previous
//
#include <hip/hip_runtime.h>

#define DEV __device__ __forceinline__

typedef _Float16 f16x8 __attribute__((ext_vector_type(8)));
typedef _Float16 f16x4 __attribute__((ext_vector_type(4)));
typedef unsigned short u16x8 __attribute__((ext_vector_type(8)));
typedef float f32x4 __attribute__((ext_vector_type(4)));

// async global->LDS, 16B per lane. LDS dest must be wave-uniform base (+lane*16 in HW).
DEV void glds16(const void* g, void* l) {
    __builtin_amdgcn_global_load_lds(
        (const __attribute__((address_space(1))) void*)g,
        (__attribute__((address_space(3))) void*)l, 16, 0, 0);
}

// ---------------------------------------------------------------------------
// cast fp32 -> fp16, 4 elems/thread
__global__ __launch_bounds__(256) void cast_f32_f16(const float* __restrict__ src,
                                                    _Float16* __restrict__ dst, int n4) {
    const int i = blockIdx.x * 256 + threadIdx.x;
    if (i >= n4) return;
    const float4 v = ((const float4*)src)[i];
    f16x4 o = { (_Float16)v.x, (_Float16)v.y, (_Float16)v.z, (_Float16)v.w };
    *(f16x4*)(dst + (size_t)i * 4) = o;
}

// ---------------------------------------------------------------------------
// Fold LoRA (I + A B) into Q/V sections of Wqkv; fold softmax scale into Q.
__global__ __launch_bounds__(256) void prep_w(const float* __restrict__ W,
                                              const float* __restrict__ Aq,
                                              const float* __restrict__ Bq,
                                              const float* __restrict__ Av,
                                              const float* __restrict__ Bv,
                                              _Float16* __restrict__ Wb) {
    const int bx = blockIdx.x;         // 0..23: 12 Q heads then 12 V heads
    const int sec = bx / 12;           // 0 = Q, 1 = V
    const int h = bx - sec * 12;
    const float* Am = sec ? Av : Aq;   // [64][4]
    const float* Bm = sec ? Bv : Bq;   // [4][64]
    const int base = sec ? (1536 + h * 64) : (h * 64);
    const float scale = sec ? 1.0f : 0.125f;   // hd^-0.5 folded into Q
    for (int c = threadIdx.x; c < 768; c += 256) {
        float t0 = 0.f, t1 = 0.f, t2 = 0.f, t3 = 0.f;
        for (int j = 0; j < 64; ++j) {
            const float w = W[(size_t)(base + j) * 768 + c];
            t0 += Am[j * 4 + 0] * w;
            t1 += Am[j * 4 + 1] * w;
            t2 += Am[j * 4 + 2] * w;
            t3 += Am[j * 4 + 3] * w;
        }
        for (int i = 0; i < 64; ++i) {
            const float w = W[(size_t)(base + i) * 768 + c];
            const float val = w + t0 * Bm[i] + t1 * Bm[64 + i] + t2 * Bm[128 + i] + t3 * Bm[192 + i];
            Wb[(size_t)(base + i) * 768 + c] = (_Float16)(val * scale);
        }
    }
}

// ---------------------------------------------------------------------------
// 128x128 NT GEMM, BK=64, 4 waves (2x2 of 64x64), fp16 in / fp32 acc.
// EPI 0: scatter into Q[96][1024][64], K[96][1024][64], V^T[96][64][1024] fp16.
// EPI 1: +bias, fp32 out [M][768].
template <int EPI>
__global__ __launch_bounds__(256) void gemm_nt(const _Float16* __restrict__ A,
                                               const _Float16* __restrict__ B,
                                               int Kdim, void* __restrict__ Cout,
                                               const float* __restrict__ bias) {
    __shared__ __align__(16) _Float16 As[128 * 64];
    __shared__ __align__(16) _Float16 Bs[128 * 64];
    const int tid = threadIdx.x;
    const int lane = tid & 63, wid = tid >> 6;
    const int l15 = lane & 15, l16 = lane >> 4;
    const int m0 = blockIdx.x << 7, n0 = blockIdx.y << 7;
    const int wm = (wid >> 1) << 6, wn = (wid & 1) << 6;

    f32x4 acc[4][4];
#pragma unroll
    for (int i = 0; i < 4; ++i)
#pragma unroll
        for (int j = 0; j < 4; ++j) acc[i][j] = (f32x4){0.f, 0.f, 0.f, 0.f};

    for (int k0 = 0; k0 < Kdim; k0 += 64) {
        __syncthreads();
        // stage A,B tiles: linear LDS dest, inverse-swizzled global source (rule 21)
#pragma unroll
        for (int rr = 0; rr < 4; ++rr) {
            const int slot = (rr << 8) + tid;          // 0..1023
            const int row = slot >> 3, sl = slot & 7;  // 8B-elem slices of 8
            const int ldsb = ((rr << 8) + (wid << 6)) << 4;  // wave-uniform byte base
            glds16(A + (size_t)(m0 + row) * Kdim + k0 + ((sl ^ (row & 7)) << 3),
                   (char*)As + ldsb);
            glds16(B + (size_t)(n0 + row) * Kdim + k0 + ((sl ^ (row & 7)) << 3),
                   (char*)Bs + ldsb);
        }
        __syncthreads();
#pragma unroll
        for (int kh = 0; kh < 2; ++kh) {
            f16x8 af[4], bfr[4];
#pragma unroll
            for (int i = 0; i < 4; ++i) {
                const int ra = wm + i * 16 + l15;
                af[i] = *(const f16x8*)((const char*)As + ra * 128 +
                                        ((((kh << 2) + l16) ^ (ra & 7)) << 4));
                const int rb = wn + i * 16 + l15;
                bfr[i] = *(const f16x8*)((const char*)Bs + rb * 128 +
                                         ((((kh << 2) + l16) ^ (rb & 7)) << 4));
            }
#pragma unroll
            for (int i = 0; i < 4; ++i)
#pragma unroll
                for (int j = 0; j < 4; ++j)
                    acc[i][j] = __builtin_amdgcn_mfma_f32_16x16x32_f16(af[i], bfr[j], acc[i][j], 0, 0, 0);
        }
    }

    if (EPI == 0) {
        _Float16* qkv = (_Float16*)Cout;
#pragma unroll
        for (int j = 0; j < 4; ++j) {
            const int col = n0 + wn + j * 16 + l15;   // 0..2303 = [3][12][64]
            const int which = col / 768;
            const int rem = col - which * 768;
            const int hh = rem >> 6, d = rem & 63;
#pragma unroll
            for (int i = 0; i < 4; ++i) {
                const int rowb = m0 + wm + i * 16 + (l16 << 2);  // b*1024+n, 4-aligned
                const int b = rowb >> 10, n = rowb & 1023;
                const int b12h = b * 12 + hh;
                if (which == 2) {
                    // V transposed: VT[bh][d][n], 4 consecutive n -> 8B store
                    f16x4 pk = { (_Float16)acc[i][j][0], (_Float16)acc[i][j][1],
                                 (_Float16)acc[i][j][2], (_Float16)acc[i][j][3] };
                    *(f16x4*)(qkv + 12582912 + (((size_t)b12h * 64 + d) << 10) + n) = pk;
                } else {
#pragma unroll
                    for (int r = 0; r < 4; ++r) {
                        const size_t idx = (size_t)which * 6291456 +
                                           (((size_t)b12h << 10) + n + r) * 64 + d;
                        qkv[idx] = (_Float16)acc[i][j][r];
                    }
                }
            }
        }
    } else {
        float* out = (float*)Cout;
#pragma unroll
        for (int j = 0; j < 4; ++j) {
            const int col = n0 + wn + j * 16 + l15;
            const float bv = bias[col];
#pragma unroll
            for (int i = 0; i < 4; ++i)
#pragma unroll
                for (int r = 0; r < 4; ++r) {
                    const int row = m0 + wm + i * 16 + (l16 << 2) + r;
                    out[(size_t)row * 768 + col] = acc[i][j][r] + bv;
                }
        }
    }
}

// ---------------------------------------------------------------------------
// Flash attention, waves fully independent (no __syncthreads, no K/V staging).
// K read direct from global [bh][kv][64] (B-frag = contiguous 16B).
// V read direct from global V^T [bh][64][kv] (B-frag = contiguous 16B).
// Only per-wave P round-trip uses LDS (8KB/wave). Scale folded into Q upstream.
// grid = (96 bh, 8 qblocks): bh%8 -> stable XCD per head => K/V L2-resident.
__global__ __launch_bounds__(256) void attn_kernel(const _Float16* __restrict__ Qg,
                                                   const _Float16* __restrict__ Kg,
                                                   const _Float16* __restrict__ VTg,
                                                   _Float16* __restrict__ AO) {
    __shared__ __align__(16) _Float16 Ps[4][32 * 128];

    const int tid = threadIdx.x, lane = tid & 63, wid = tid >> 6;
    const int l15 = lane & 15, l16 = lane >> 4;
    const int bh = blockIdx.x;             // b*12+h
    const int q0 = blockIdx.y << 7;
    const _Float16* Kh = Kg + ((size_t)bh << 16);    // [1024][64]
    const _Float16* VTh = VTg + ((size_t)bh << 16);  // [64][1024]

    // hoist Q fragments (wave owns rows q0 + wid*32 .. +31)
    f16x8 qf[2][2];
#pragma unroll
    for (int mt = 0; mt < 2; ++mt)
#pragma unroll
        for (int kh = 0; kh < 2; ++kh) {
            const int row = q0 + (wid << 5) + mt * 16 + l15;
            qf[mt][kh] = *(const f16x8*)(Qg + (((size_t)bh << 10) + row) * 64 +
                                         (((kh << 2) + l16) << 3));
        }

    f32x4 o[2][4];
    float m_run[2][4], l_run[2][4];
#pragma unroll
    for (int mt = 0; mt < 2; ++mt)
#pragma unroll
        for (int rg = 0; rg < 4; ++rg) {
            m_run[mt][rg] = -INFINITY;
            l_run[mt][rg] = 0.f;
        }
#pragma unroll
    for (int mt = 0; mt < 2; ++mt)
#pragma unroll
        for (int nf = 0; nf < 4; ++nf) o[mt][nf] = (f32x4){0.f, 0.f, 0.f, 0.f};

    char* Pb = (char*)&Ps[wid][0];

    for (int kt = 0; kt < 8; ++kt) {
        const int kv0 = kt << 7;

        // S = Q K^T (K B-frags direct from global, contiguous 16B, L2-served)
        f32x4 s[2][8];
#pragma unroll
        for (int mt = 0; mt < 2; ++mt)
#pragma unroll
            for (int nf = 0; nf < 8; ++nf) s[mt][nf] = (f32x4){0.f, 0.f, 0.f, 0.f};
#pragma unroll
        for (int kh = 0; kh < 2; ++kh) {
            f16x8 kf[8];
#pragma unroll
            for (int nf = 0; nf < 8; ++nf)
                kf[nf] = *(const f16x8*)(Kh + (size_t)(kv0 + nf * 16 + l15) * 64 +
                                         (((kh << 2) + l16) << 3));
            __builtin_amdgcn_s_setprio(1);
#pragma unroll
            for (int nf = 0; nf < 8; ++nf) {
                s[0][nf] = __builtin_amdgcn_mfma_f32_16x16x32_f16(qf[0][kh], kf[nf], s[0][nf], 0, 0, 0);
                s[1][nf] = __builtin_amdgcn_mfma_f32_16x16x32_f16(qf[1][kh], kf[nf], s[1][nf], 0, 0, 0);
            }
            __builtin_amdgcn_s_setprio(0);
        }

        // online softmax (rows live on 16-lane groups; reduce over l15)
        float fac[2][4];
#pragma unroll
        for (int mt = 0; mt < 2; ++mt)
#pragma unroll
            for (int rg = 0; rg < 4; ++rg) {
                float mx = s[mt][0][rg];
#pragma unroll
                for (int nf = 1; nf < 8; ++nf) mx = fmaxf(mx, s[mt][nf][rg]);
                mx = fmaxf(mx, __shfl_xor(mx, 1));
                mx = fmaxf(mx, __shfl_xor(mx, 2));
                mx = fmaxf(mx, __shfl_xor(mx, 4));
                mx = fmaxf(mx, __shfl_xor(mx, 8));
                const float mnew = fmaxf(m_run[mt][rg], mx);
                const float f = __expf(m_run[mt][rg] - mnew);
                fac[mt][rg] = f;
                float sum = 0.f;
#pragma unroll
                for (int nf = 0; nf < 8; ++nf) {
                    const float p0 = __expf(s[mt][nf][rg] - mnew);
                    s[mt][nf][rg] = p0;
                    sum += p0;
                }
                sum += __shfl_xor(sum, 1);
                sum += __shfl_xor(sum, 2);
                sum += __shfl_xor(sum, 4);
                sum += __shfl_xor(sum, 8);
                l_run[mt][rg] = l_run[mt][rg] * f + sum;
                m_run[mt][rg] = mnew;
            }

        // write P (fp16) to per-wave LDS, swizzled
#pragma unroll
        for (int mt = 0; mt < 2; ++mt)
#pragma unroll
            for (int nf = 0; nf < 8; ++nf)
#pragma unroll
                for (int rg = 0; rg < 4; ++rg) {
                    const int row = mt * 16 + (l16 << 2) + rg;
                    const int col = nf * 16 + l15;
                    *(_Float16*)(Pb + ((row * 256 + col * 2) ^ ((row & 7) << 4))) =
                        (_Float16)s[mt][nf][rg];
                }

        // rescale O
#pragma unroll
        for (int mt = 0; mt < 2; ++mt)
#pragma unroll
            for (int nf = 0; nf < 4; ++nf)
#pragma unroll
                for (int rg = 0; rg < 4; ++rg) o[mt][nf][rg] *= fac[mt][rg];

        asm volatile("s_waitcnt lgkmcnt(0)" ::: "memory");

        // O += P @ V  (V B-frags direct from global V^T, contiguous 16B)
#pragma unroll
        for (int ks = 0; ks < 4; ++ks) {
            f16x8 vf[4];
#pragma unroll
            for (int nf = 0; nf < 4; ++nf)
                vf[nf] = *(const f16x8*)(VTh + (size_t)(nf * 16 + l15) * 1024 + kv0 +
                                         (((ks << 2) + l16) << 3));
            __builtin_amdgcn_s_setprio(1);
#pragma unroll
            for (int mt = 0; mt < 2; ++mt) {
                const int prow = mt * 16 + l15;
                const f16x8 pa = *(const f16x8*)(Pb + prow * 256 +
                                                 ((((ks << 2) + l16) ^ (prow & 7)) << 4));
#pragma unroll
                for (int nf = 0; nf < 4; ++nf)
                    o[mt][nf] = __builtin_amdgcn_mfma_f32_16x16x32_f16(pa, vf[nf], o[mt][nf], 0, 0, 0);
            }
            __builtin_amdgcn_s_setprio(0);
        }
    }

    // epilogue: AO[b, n, h*64+d] = O / l
    const int b = bh / 12, h = bh - (bh / 12) * 12;
#pragma unroll
    for (int mt = 0; mt < 2; ++mt)
#pragma unroll
        for (int rg = 0; rg < 4; ++rg) {
            const float inv = 1.0f / l_run[mt][rg];
            const int n = q0 + (wid << 5) + mt * 16 + (l16 << 2) + rg;
#pragma unroll
            for (int nf = 0; nf < 4; ++nf) {
                const int d = nf * 16 + l15;
                AO[((size_t)b * 1024 + n) * 768 + h * 64 + d] = (_Float16)(o[mt][nf][rg] * inv);
            }
        }
}

// ---------------------------------------------------------------------------
extern "C" void kernel_launch(void* const* d_in, const int* in_sizes, int n_in,
                              void* d_out, int out_size, void* d_ws, size_t ws_size,
                              hipStream_t stream) {
    (void)in_sizes; (void)n_in; (void)out_size; (void)ws_size;
    const float* x     = (const float*)d_in[0];
    const float* Wqkv  = (const float*)d_in[1];
    const float* Wproj = (const float*)d_in[2];
    const float* bproj = (const float*)d_in[3];
    const float* Aq    = (const float*)d_in[4];
    const float* Bq    = (const float*)d_in[5];
    const float* Av    = (const float*)d_in[6];
    const float* Bv    = (const float*)d_in[7];

    // workspace layout (fp16 elements)
    _Float16* Xb     = (_Float16*)d_ws;          // [8192][768]
    _Float16* Wqkvb  = Xb + 6291456;             // [2304][768]
    _Float16* Wprojb = Wqkvb + 1769472;          // [768][768]
    _Float16* QKV    = Wprojb + 589824;          // Q[96][1024][64] K[96][1024][64] VT[96][64][1024]
    _Float16* AO     = QKV + 18874368;           // [8192][768]
    float* out = (float*)d_out;

    cast_f32_f16<<<6144, 256, 0, stream>>>(x, Xb, 1572864);
    cast_f32_f16<<<576, 256, 0, stream>>>(Wqkv + 589824, Wqkvb + 589824, 147456);  // K rows
    cast_f32_f16<<<576, 256, 0, stream>>>(Wproj, Wprojb, 147456);
    prep_w<<<24, 256, 0, stream>>>(Wqkv, Aq, Bq, Av, Bv, Wqkvb);

    gemm_nt<0><<<dim3(64, 18), 256, 0, stream>>>(Xb, Wqkvb, 768, (void*)QKV, nullptr);
    attn_kernel<<<dim3(96, 8), 256, 0, stream>>>(QKV, QKV + 6291456, QKV + 12582912, AO);
    gemm_nt<1><<<dim3(64, 6), 256, 0, stream>>>(AO, Wprojb, 768, (void*)out, bproj);
}

// Round 4
// 193.498 us; speedup vs baseline: 1.1681x; 1.1110x over previous
//
#include <hip/hip_runtime.h>

#define DEV __device__ __forceinline__

typedef _Float16 f16x8 __attribute__((ext_vector_type(8)));
typedef _Float16 f16x4 __attribute__((ext_vector_type(4)));
typedef unsigned short u16x8 __attribute__((ext_vector_type(8)));
typedef float f32x4 __attribute__((ext_vector_type(4)));
typedef float f32x16 __attribute__((ext_vector_type(16)));
typedef unsigned int u32x4 __attribute__((ext_vector_type(4)));
typedef unsigned int u32x2 __attribute__((ext_vector_type(2)));

// async global->LDS, 16B per lane. LDS dest must be wave-uniform base (+lane*16 in HW).
DEV void glds16(const void* g, void* l) {
    __builtin_amdgcn_global_load_lds(
        (const __attribute__((address_space(1))) void*)g,
        (__attribute__((address_space(3))) void*)l, 16, 0, 0);
}

DEV unsigned pkh(float lo, float hi) {
    return __builtin_bit_cast(unsigned, __builtin_amdgcn_cvt_pkrtz(lo, hi));
}

// ---------------------------------------------------------------------------
// cast fp32 -> fp16, 4 elems/thread
__global__ __launch_bounds__(256) void cast_f32_f16(const float* __restrict__ src,
                                                    _Float16* __restrict__ dst, int n4) {
    const int i = blockIdx.x * 256 + threadIdx.x;
    if (i >= n4) return;
    const float4 v = ((const float4*)src)[i];
    f16x4 o = { (_Float16)v.x, (_Float16)v.y, (_Float16)v.z, (_Float16)v.w };
    *(f16x4*)(dst + (size_t)i * 4) = o;
}

// ---------------------------------------------------------------------------
// Fold LoRA (I + A B) into Q/V sections of Wqkv; fold softmax scale AND log2(e)
// into Q (attention uses exp2-domain softmax).
__global__ __launch_bounds__(256) void prep_w(const float* __restrict__ W,
                                              const float* __restrict__ Aq,
                                              const float* __restrict__ Bq,
                                              const float* __restrict__ Av,
                                              const float* __restrict__ Bv,
                                              _Float16* __restrict__ Wb) {
    const int bx = blockIdx.x;         // 0..23: 12 Q heads then 12 V heads
    const int sec = bx / 12;           // 0 = Q, 1 = V
    const int h = bx - sec * 12;
    const float* Am = sec ? Av : Aq;   // [64][4]
    const float* Bm = sec ? Bv : Bq;   // [4][64]
    const int base = sec ? (1536 + h * 64) : (h * 64);
    const float scale = sec ? 1.0f : (0.125f * 1.4426950408889634f);
    for (int c = threadIdx.x; c < 768; c += 256) {
        float t0 = 0.f, t1 = 0.f, t2 = 0.f, t3 = 0.f;
        for (int j = 0; j < 64; ++j) {
            const float w = W[(size_t)(base + j) * 768 + c];
            t0 += Am[j * 4 + 0] * w;
            t1 += Am[j * 4 + 1] * w;
            t2 += Am[j * 4 + 2] * w;
            t3 += Am[j * 4 + 3] * w;
        }
        for (int i = 0; i < 64; ++i) {
            const float w = W[(size_t)(base + i) * 768 + c];
            const float val = w + t0 * Bm[i] + t1 * Bm[64 + i] + t2 * Bm[128 + i] + t3 * Bm[192 + i];
            Wb[(size_t)(base + i) * 768 + c] = (_Float16)(val * scale);
        }
    }
}

// ---------------------------------------------------------------------------
// 128x128 NT GEMM, BK=64, 4 waves (2x2 of 64x64), fp16 in / fp32 acc.
// EPI 0: scatter into Q[96][1024][64], K[96][1024][64], V^T[96][64][1024] fp16.
// EPI 1: +bias, fp32 out [M][768].
template <int EPI>
__global__ __launch_bounds__(256) void gemm_nt(const _Float16* __restrict__ A,
                                               const _Float16* __restrict__ B,
                                               int Kdim, void* __restrict__ Cout,
                                               const float* __restrict__ bias) {
    __shared__ __align__(16) _Float16 As[128 * 64];
    __shared__ __align__(16) _Float16 Bs[128 * 64];
    const int tid = threadIdx.x;
    const int lane = tid & 63, wid = tid >> 6;
    const int l15 = lane & 15, l16 = lane >> 4;
    const int m0 = blockIdx.x << 7, n0 = blockIdx.y << 7;
    const int wm = (wid >> 1) << 6, wn = (wid & 1) << 6;

    f32x4 acc[4][4];
#pragma unroll
    for (int i = 0; i < 4; ++i)
#pragma unroll
        for (int j = 0; j < 4; ++j) acc[i][j] = (f32x4){0.f, 0.f, 0.f, 0.f};

    for (int k0 = 0; k0 < Kdim; k0 += 64) {
        __syncthreads();
        // stage A,B tiles: linear LDS dest, inverse-swizzled global source (rule 21)
#pragma unroll
        for (int rr = 0; rr < 4; ++rr) {
            const int slot = (rr << 8) + tid;          // 0..1023
            const int row = slot >> 3, sl = slot & 7;  // 8B-elem slices of 8
            const int ldsb = ((rr << 8) + (wid << 6)) << 4;  // wave-uniform byte base
            glds16(A + (size_t)(m0 + row) * Kdim + k0 + ((sl ^ (row & 7)) << 3),
                   (char*)As + ldsb);
            glds16(B + (size_t)(n0 + row) * Kdim + k0 + ((sl ^ (row & 7)) << 3),
                   (char*)Bs + ldsb);
        }
        __syncthreads();
#pragma unroll
        for (int kh = 0; kh < 2; ++kh) {
            f16x8 af[4], bfr[4];
#pragma unroll
            for (int i = 0; i < 4; ++i) {
                const int ra = wm + i * 16 + l15;
                af[i] = *(const f16x8*)((const char*)As + ra * 128 +
                                        ((((kh << 2) + l16) ^ (ra & 7)) << 4));
                const int rb = wn + i * 16 + l15;
                bfr[i] = *(const f16x8*)((const char*)Bs + rb * 128 +
                                         ((((kh << 2) + l16) ^ (rb & 7)) << 4));
            }
#pragma unroll
            for (int i = 0; i < 4; ++i)
#pragma unroll
                for (int j = 0; j < 4; ++j)
                    acc[i][j] = __builtin_amdgcn_mfma_f32_16x16x32_f16(af[i], bfr[j], acc[i][j], 0, 0, 0);
        }
    }

    if (EPI == 0) {
        _Float16* qkv = (_Float16*)Cout;
#pragma unroll
        for (int j = 0; j < 4; ++j) {
            const int col = n0 + wn + j * 16 + l15;   // 0..2303 = [3][12][64]
            const int which = col / 768;
            const int rem = col - which * 768;
            const int hh = rem >> 6, d = rem & 63;
#pragma unroll
            for (int i = 0; i < 4; ++i) {
                const int rowb = m0 + wm + i * 16 + (l16 << 2);  // b*1024+n, 4-aligned
                const int b = rowb >> 10, n = rowb & 1023;
                const int b12h = b * 12 + hh;
                if (which == 2) {
                    // V transposed: VT[bh][d][n], 4 consecutive n -> 8B store
                    f16x4 pk = { (_Float16)acc[i][j][0], (_Float16)acc[i][j][1],
                                 (_Float16)acc[i][j][2], (_Float16)acc[i][j][3] };
                    *(f16x4*)(qkv + 12582912 + (((size_t)b12h * 64 + d) << 10) + n) = pk;
                } else {
#pragma unroll
                    for (int r = 0; r < 4; ++r) {
                        const size_t idx = (size_t)which * 6291456 +
                                           (((size_t)b12h << 10) + n + r) * 64 + d;
                        qkv[idx] = (_Float16)acc[i][j][r];
                    }
                }
            }
        }
    } else {
        float* out = (float*)Cout;
#pragma unroll
        for (int j = 0; j < 4; ++j) {
            const int col = n0 + wn + j * 16 + l15;
            const float bv = bias[col];
#pragma unroll
            for (int i = 0; i < 4; ++i)
#pragma unroll
                for (int r = 0; r < 4; ++r) {
                    const int row = m0 + wm + i * 16 + (l16 << 2) + r;
                    out[(size_t)row * 768 + col] = acc[i][j][r] + bv;
                }
        }
    }
}

// ---------------------------------------------------------------------------
// Flash attention, swapped-operand structure, 32x32x16 MFMA.
// Each lane owns ONE q row (q = lane&31): softmax in-lane + 1 cross-half shfl.
// S^T = mfma(K, Q); O^T = mfma(VT, P^T). P fragments built in-register via
// cvt_pkrtz + __shfl_xor(.,32) (explicit, semantics-safe) + per-half select.
// Lane's st[reg] covers kv=(reg&3)+8*(reg>>2)+4*hi; B-frag word w needs
// kv pair (2w,2w+1)+8*hi per 16-kv slice -> cross-half word exchange.
// No LDS, no barriers; waves fully independent.
__global__ __launch_bounds__(256) void attn_kernel(const _Float16* __restrict__ Qg,
                                                   const _Float16* __restrict__ Kg,
                                                   const _Float16* __restrict__ VTg,
                                                   _Float16* __restrict__ AO) {
    const int tid = threadIdx.x, lane = tid & 63, wid = tid >> 6;
    const int l31 = lane & 31, hi = lane >> 5;
    const int bh = blockIdx.x;             // b*12+h
    const int q = (blockIdx.y << 7) + (wid << 5) + l31;   // this lane's q row
    const _Float16* Kh = Kg + ((size_t)bh << 16);    // [1024][64]
    const _Float16* VTh = VTg + ((size_t)bh << 16);  // [64][1024]

    // Q fragments (B-operand): lane holds Q[q][kd*16 + hi*8 + j]
    f16x8 qf[4];
#pragma unroll
    for (int kd = 0; kd < 4; ++kd)
        qf[kd] = *(const f16x8*)(Qg + (((size_t)bh << 10) + q) * 64 + kd * 16 + hi * 8);

    f32x16 o0, o1;   // O^T acc, d-tiles [0..31],[32..63]: all values belong to q
#pragma unroll
    for (int j = 0; j < 16; ++j) { o0[j] = 0.f; o1[j] = 0.f; }
    float m_run = -INFINITY, l_run = 0.f;

    f16x8 kf[4], vf[4];
#pragma unroll
    for (int kd = 0; kd < 4; ++kd)
        kf[kd] = *(const f16x8*)(Kh + (size_t)l31 * 64 + kd * 16 + hi * 8);

    for (int kt = 0; kt < 32; ++kt) {
        const int kv0 = kt << 5;

        // S^T[kv][q] = sum_d K[kv][d] * Q[q][d]
        f32x16 st;
#pragma unroll
        for (int j = 0; j < 16; ++j) st[j] = 0.f;
        __builtin_amdgcn_s_setprio(1);
#pragma unroll
        for (int kd = 0; kd < 4; ++kd)
            st = __builtin_amdgcn_mfma_f32_32x32x16_f16(kf[kd], qf[kd], st, 0, 0, 0);
        __builtin_amdgcn_s_setprio(0);

        // prefetch next K tile straight into kf (WAR after MFMA issue; latency
        // hides under softmax+PV). Wraps to tile 0 on last iter (harmless).
        const int kvn = ((kt + 1) & 31) << 5;
#pragma unroll
        for (int kd = 0; kd < 4; ++kd)
            kf[kd] = *(const f16x8*)(Kh + (size_t)(kvn + l31) * 64 + kd * 16 + hi * 8);
        // issue V loads early (consumed after softmax)
#pragma unroll
        for (int t = 0; t < 2; ++t)
#pragma unroll
            for (int ks = 0; ks < 2; ++ks)
                vf[t * 2 + ks] = *(const f16x8*)(VTh + (size_t)(t * 32 + l31) * 1024 +
                                                 kv0 + ks * 16 + hi * 8);

        // ---- in-lane online softmax (16 values of row q; other half in lane^32)
        float mx = fmaxf(st[0], st[1]);
#pragma unroll
        for (int j = 2; j < 16; ++j) mx = fmaxf(mx, st[j]);
        mx = fmaxf(mx, __shfl_xor(mx, 32));
        const float mnew = fmaxf(m_run, mx);
        const float fac = __builtin_amdgcn_exp2f(m_run - mnew);
        float p[16];
        float sum = 0.f;
#pragma unroll
        for (int j = 0; j < 16; ++j) {
            p[j] = __builtin_amdgcn_exp2f(st[j] - mnew);
            sum += p[j];
        }
        sum += __shfl_xor(sum, 32);
        l_run = l_run * fac + sum;
        m_run = mnew;
        // rescale O^T (scalar fac -- all o values belong to this lane's q)
#pragma unroll
        for (int j = 0; j < 16; ++j) { o0[j] *= fac; o1[j] *= fac; }

        // ---- build PV B-fragments: p[r] holds kv=(r&3)+8*(r>>2)+4*hi.
        // Word w of B-frag slice s must hold kv pair (s*16 + hi*8 + 2w, +1).
        const unsigned a0 = pkh(p[0], p[1]),   a1 = pkh(p[2], p[3]);
        const unsigned a2 = pkh(p[4], p[5]),   a3 = pkh(p[6], p[7]);
        const unsigned a4 = pkh(p[8], p[9]),   a5 = pkh(p[10], p[11]);
        const unsigned a6 = pkh(p[12], p[13]), a7 = pkh(p[14], p[15]);
        const unsigned b0 = (unsigned)__shfl_xor((int)a0, 32);
        const unsigned b1 = (unsigned)__shfl_xor((int)a1, 32);
        const unsigned b2 = (unsigned)__shfl_xor((int)a2, 32);
        const unsigned b3 = (unsigned)__shfl_xor((int)a3, 32);
        const unsigned b4 = (unsigned)__shfl_xor((int)a4, 32);
        const unsigned b5 = (unsigned)__shfl_xor((int)a5, 32);
        const unsigned b6 = (unsigned)__shfl_xor((int)a6, 32);
        const unsigned b7 = (unsigned)__shfl_xor((int)a7, 32);
        // slice kv[0..15]: hi=0 wants kv0..7 (own a0,a1 | partner b0,b1)
        //                  hi=1 wants kv8..15 (partner b2,b3 | own a2,a3)
        const u32x4 w0 = { hi ? b2 : a0, hi ? b3 : a1, hi ? a2 : b0, hi ? a3 : b1 };
        // slice kv[16..31]: same pattern on a4..a7
        const u32x4 w1 = { hi ? b6 : a4, hi ? b7 : a5, hi ? a6 : b4, hi ? a7 : b5 };
        const f16x8 pa0 = __builtin_bit_cast(f16x8, w0);  // kv 0..15 slice
        const f16x8 pa1 = __builtin_bit_cast(f16x8, w1);  // kv 16..31 slice

        // O^T[d][q] += sum_kv VT[d][kv] * P[q][kv]
        __builtin_amdgcn_s_setprio(1);
        o0 = __builtin_amdgcn_mfma_f32_32x32x16_f16(vf[0], pa0, o0, 0, 0, 0);
        o0 = __builtin_amdgcn_mfma_f32_32x32x16_f16(vf[1], pa1, o0, 0, 0, 0);
        o1 = __builtin_amdgcn_mfma_f32_32x32x16_f16(vf[2], pa0, o1, 0, 0, 0);
        o1 = __builtin_amdgcn_mfma_f32_32x32x16_f16(vf[3], pa1, o1, 0, 0, 0);
        __builtin_amdgcn_s_setprio(0);
    }

    // epilogue: AO[b][n=q][h*64+d] = O^T[d][q] / l;  d = t*32 + g*8 + hi*4 + i
    const float inv = __builtin_amdgcn_rcpf(l_run);
    const int b = bh / 12, h = bh - (bh / 12) * 12;
    _Float16* dst = AO + ((size_t)b * 1024 + q) * 768 + h * 64 + hi * 4;
#pragma unroll
    for (int g = 0; g < 4; ++g) {
        const u32x2 w0 = { pkh(o0[4 * g + 0] * inv, o0[4 * g + 1] * inv),
                           pkh(o0[4 * g + 2] * inv, o0[4 * g + 3] * inv) };
        *(f16x4*)(dst + g * 8) = __builtin_bit_cast(f16x4, w0);
        const u32x2 w1 = { pkh(o1[4 * g + 0] * inv, o1[4 * g + 1] * inv),
                           pkh(o1[4 * g + 2] * inv, o1[4 * g + 3] * inv) };
        *(f16x4*)(dst + 32 + g * 8) = __builtin_bit_cast(f16x4, w1);
    }
}

// ---------------------------------------------------------------------------
extern "C" void kernel_launch(void* const* d_in, const int* in_sizes, int n_in,
                              void* d_out, int out_size, void* d_ws, size_t ws_size,
                              hipStream_t stream) {
    (void)in_sizes; (void)n_in; (void)out_size; (void)ws_size;
    const float* x     = (const float*)d_in[0];
    const float* Wqkv  = (const float*)d_in[1];
    const float* Wproj = (const float*)d_in[2];
    const float* bproj = (const float*)d_in[3];
    const float* Aq    = (const float*)d_in[4];
    const float* Bq    = (const float*)d_in[5];
    const float* Av    = (const float*)d_in[6];
    const float* Bv    = (const float*)d_in[7];

    // workspace layout (fp16 elements)
    _Float16* Xb     = (_Float16*)d_ws;          // [8192][768]
    _Float16* Wqkvb  = Xb + 6291456;             // [2304][768]
    _Float16* Wprojb = Wqkvb + 1769472;          // [768][768]
    _Float16* QKV    = Wprojb + 589824;          // Q[96][1024][64] K[96][1024][64] VT[96][64][1024]
    _Float16* AO     = QKV + 18874368;           // [8192][768]
    float* out = (float*)d_out;

    cast_f32_f16<<<6144, 256, 0, stream>>>(x, Xb, 1572864);
    cast_f32_f16<<<576, 256, 0, stream>>>(Wqkv + 589824, Wqkvb + 589824, 147456);  // K rows
    cast_f32_f16<<<576, 256, 0, stream>>>(Wproj, Wprojb, 147456);
    prep_w<<<24, 256, 0, stream>>>(Wqkv, Aq, Bq, Av, Bv, Wqkvb);

    gemm_nt<0><<<dim3(64, 18), 256, 0, stream>>>(Xb, Wqkvb, 768, (void*)QKV, nullptr);
    attn_kernel<<<dim3(96, 8), 256, 0, stream>>>(QKV, QKV + 6291456, QKV + 12582912, AO);
    gemm_nt<1><<<dim3(64, 6), 256, 0, stream>>>(AO, Wprojb, 768, (void*)out, bproj);
}